// Round 6
// baseline (463.923 us; speedup 1.0000x reference)
//
#include <hip/hip_runtime.h>
#include <math.h>

// Problem constants: B=64/side (128 concat), d=256, C=128, S=1024, TEMP=0.1, COEFF=0.5
#define TEMP_INV 10.0f

typedef unsigned long long u64;
typedef __attribute__((ext_vector_type(8))) __bf16 bf16x8;
typedef __attribute__((ext_vector_type(4))) float f32x4;

// Monotone u32 key: fkey(a) > fkey(b) iff a > b (floats, no NaN).
__device__ inline unsigned fkey(float v) {
  unsigned u = __float_as_uint(v);
  return (u & 0x80000000u) ? ~u : (u | 0x80000000u);
}
// bf16-pair (u32) -> floats
__device__ inline float bl16(unsigned u) { return __uint_as_float(u << 16); }
__device__ inline float bh16(unsigned u) { return __uint_as_float(u & 0xFFFF0000u); }

// ---------- fused transpose + bf16 convert + norms: of -> ofT ----------
__global__ __launch_bounds__(256) void kcvt(const float* __restrict__ ofq,
                                            const float* __restrict__ ofk,
                                            __bf16* __restrict__ ofT,
                                            float* __restrict__ of_invn) {
  int s0 = blockIdx.x * 32, b = blockIdx.y;
  const float* src = (b < 64) ? (ofq + (size_t)b * 262144) : (ofk + (size_t)(b - 64) * 262144);
  __shared__ __bf16 T[32][36];
  __shared__ float R[8][32];
  int t = threadIdx.x;
  int dd = t >> 5, ss = t & 31;
  int wr = t >> 3, wd = t & 7;
  float ssq = 0.f;
  __bf16* out = ofT + (size_t)b * 262144 + (size_t)s0 * 256;
  for (int d0 = 0; d0 < 256; d0 += 32) {
    float v[4];
#pragma unroll
    for (int it = 0; it < 4; ++it) {
      int d = d0 + dd + 8 * it;
      v[it] = src[(size_t)d * 1024 + s0 + ss];
      ssq += v[it] * v[it];
    }
    __syncthreads();
#pragma unroll
    for (int it = 0; it < 4; ++it) T[ss][dd + 8 * it] = (__bf16)v[it];
    __syncthreads();
    *(uint2*)(out + (size_t)wr * 256 + d0 + wd * 4) = *(const uint2*)(&T[wr][wd * 4]);
  }
  R[dd][ss] = ssq;
  __syncthreads();
  if (t < 32) {
    float a = 0.f;
#pragma unroll
    for (int r = 0; r < 8; ++r) a += R[r][t];
    of_invn[b * 1024 + s0 + t] = 1.0f / fmaxf(sqrtf(a), 1e-12f);
  }
}

// ---------- x -> xT bf16 [side(2)*64][1024 s][128 c] + x_invn + ad16 ----------
__global__ __launch_bounds__(256) void kcvt_x(const float* __restrict__ xq,
                                              const float* __restrict__ xk,
                                              __bf16* __restrict__ xT,
                                              float* __restrict__ x_invn,
                                              const float* __restrict__ adq,
                                              const float* __restrict__ adk,
                                              __bf16* __restrict__ ad16) {
  int y = blockIdx.y, t = threadIdx.x;
  if (y == 128) {  // ad16[dir][j][c]: dir0=adk, dir1=adq (natural [j][c] layout)
    int i = blockIdx.x * 512 + t * 2;  // 0..16383
    const float* src = (i < 8192) ? adk : adq;
    int r = i & 8191;
    ad16[i] = (__bf16)src[r];
    ad16[i + 1] = (__bf16)src[r + 1];
    return;
  }
  int s0 = blockIdx.x * 32, b = y;
  const float* src = (b < 64) ? (xq + (size_t)b * 131072) : (xk + (size_t)(b - 64) * 131072);
  __shared__ __bf16 T[32][36];
  __shared__ float R[8][32];
  int dd = t >> 5, ss = t & 31;
  int wr = t >> 3, wd = t & 7;
  float ssq = 0.f;
  __bf16* out = xT + (size_t)b * 131072 + (size_t)s0 * 128;
  for (int d0 = 0; d0 < 128; d0 += 32) {
    float v[4];
#pragma unroll
    for (int it = 0; it < 4; ++it) {
      int d = d0 + dd + 8 * it;
      v[it] = src[(size_t)d * 1024 + s0 + ss];
      ssq += v[it] * v[it];
    }
    __syncthreads();
#pragma unroll
    for (int it = 0; it < 4; ++it) T[ss][dd + 8 * it] = (__bf16)v[it];
    __syncthreads();
    *(uint2*)(out + (size_t)wr * 128 + d0 + wd * 4) = *(const uint2*)(&T[wr][wd * 4]);
  }
  R[dd][ss] = ssq;
  __syncthreads();
  if (t < 32) {
    float a = 0.f;
#pragma unroll
    for (int r = 0; r < 8; ++r) a += R[r][t];
    x_invn[b * 1024 + s0 + t] = 1.0f / fmaxf(sqrtf(a), 1e-12f);
  }
}

// ---------- MFMA sim GEMM + dual argmax: LDS-FREE ----------
// ofT rows are k-contiguous, so each lane's A/B fragment is one aligned 16B
// global load. No LDS, no __syncthreads -> compiler pipelines loads with
// fine-grained vmcnt across the fully-unrolled K loop.
__global__ __launch_bounds__(256) void ksim(
    const __bf16* __restrict__ ofT, const float* __restrict__ of_invn,
    u64* __restrict__ best_row, u64* __restrict__ best_col) {
  int b = blockIdx.z;
  int s0 = blockIdx.x * 128, t0 = blockIdx.y * 128;
  int t = threadIdx.x, lane = t & 63, w = t >> 6;
  int lc = lane & 15, q = lane >> 4;
  int wm = w & 1, wn = w >> 1;

  const __bf16* Ab = ofT + (size_t)b * 262144 + (size_t)(s0 + wm * 64) * 256 + q * 8;
  const __bf16* Bb = ofT + (size_t)(b + 64) * 262144 + (size_t)(t0 + wn * 64) * 256 + q * 8;

  f32x4 acc[4][4];
#pragma unroll
  for (int i = 0; i < 4; ++i)
#pragma unroll
    for (int j = 0; j < 4; ++j) acc[i][j] = (f32x4)(0.f);

  bf16x8 ac[4], bc[4], an[4], bn[4];
#pragma unroll
  for (int i = 0; i < 4; ++i) {
    ac[i] = *(const bf16x8*)(Ab + (i * 16 + lc) * 256);
    bc[i] = *(const bf16x8*)(Bb + (i * 16 + lc) * 256);
  }
#pragma unroll
  for (int it = 0; it < 8; ++it) {
    if (it < 7) {
      int k0 = (it + 1) * 32;
#pragma unroll
      for (int i = 0; i < 4; ++i) {
        an[i] = *(const bf16x8*)(Ab + (i * 16 + lc) * 256 + k0);
        bn[i] = *(const bf16x8*)(Bb + (i * 16 + lc) * 256 + k0);
      }
    }
#pragma unroll
    for (int i = 0; i < 4; ++i)
#pragma unroll
      for (int j = 0; j < 4; ++j)
        acc[i][j] = __builtin_amdgcn_mfma_f32_16x16x32_bf16(ac[i], bc[j], acc[i][j], 0, 0, 0);
    if (it < 7) {
#pragma unroll
      for (int i = 0; i < 4; ++i) { ac[i] = an[i]; bc[i] = bn[i]; }
    }
  }

  // ---- epilogue (f32). C/D layout: col=lane&15, row=(lane>>4)*4+reg ----
  float sk[4], sq[16];
#pragma unroll
  for (int j = 0; j < 4; ++j) sk[j] = of_invn[65536 + b * 1024 + t0 + wn * 64 + j * 16 + lc];
#pragma unroll
  for (int i = 0; i < 4; ++i)
#pragma unroll
    for (int e = 0; e < 4; ++e)
      sq[i * 4 + e] = of_invn[b * 1024 + s0 + wm * 64 + i * 16 + q * 4 + e];

  u64* browb = best_row + (size_t)b * 1024 + s0;
  u64* bcolb = best_col + (size_t)b * 1024 + t0;

  // row direction: argmax over t for fixed s (scale by sik; siq>0 dropped)
#pragma unroll
  for (int i = 0; i < 4; ++i) {
#pragma unroll
    for (int e = 0; e < 4; ++e) {
      float v[4];
#pragma unroll
      for (int j = 0; j < 4; ++j) v[j] = acc[i][j][e] * sk[j];
      float vb = fmaxf(fmaxf(v[0], v[1]), fmaxf(v[2], v[3]));
#pragma unroll
      for (int mask = 1; mask <= 8; mask <<= 1) vb = fmaxf(vb, __shfl_xor(vb, mask));
      unsigned ib = 0xFFFFFFFFu;
#pragma unroll
      for (int j = 0; j < 4; ++j) {
        unsigned cand = (v[j] == vb) ? (unsigned)(t0 + wn * 64 + j * 16 + lc) : 0xFFFFFFFFu;
        ib = min(ib, cand);
      }
#pragma unroll
      for (int mask = 1; mask <= 8; mask <<= 1) ib = min(ib, __shfl_xor(ib, mask));
      if (lc == 0)
        atomicMax(browb + wm * 64 + i * 16 + q * 4 + e,
                  ((u64)fkey(vb) << 32) | (u64)(0xFFFFFFFFu - ib));
    }
  }
  // col direction: argmax over s for fixed t (scale by siq)
#pragma unroll
  for (int j = 0; j < 4; ++j) {
    float cb = -INFINITY;
#pragma unroll
    for (int i = 0; i < 4; ++i)
#pragma unroll
      for (int e = 0; e < 4; ++e) cb = fmaxf(cb, acc[i][j][e] * sq[i * 4 + e]);
    cb = fmaxf(cb, __shfl_xor(cb, 16));
    cb = fmaxf(cb, __shfl_xor(cb, 32));
    unsigned ib = 0xFFFFFFFFu;
#pragma unroll
    for (int i = 0; i < 4; ++i)
#pragma unroll
      for (int e = 0; e < 4; ++e) {
        float m2 = acc[i][j][e] * sq[i * 4 + e];  // bitwise-identical recompute
        unsigned cand = (m2 == cb) ? (unsigned)(s0 + wm * 64 + i * 16 + q * 4 + e) : 0xFFFFFFFFu;
        ib = min(ib, cand);
      }
    ib = min(ib, __shfl_xor(ib, 16));
    ib = min(ib, __shfl_xor(ib, 32));
    if (lane < 16)
      atomicMax(bcolb + wn * 64 + j * 16 + lane,
                ((u64)fkey(cb) << 32) | (u64)(0xFFFFFFFFu - ib));
  }
}

// ---------- pos logits from xT (two contiguous 256B rows per output) ----------
__global__ __launch_bounds__(256) void kpos(
    const __bf16* __restrict__ xT, const float* __restrict__ x_invn,
    const u64* __restrict__ best_row, const u64* __restrict__ best_col,
    float* __restrict__ posl) {
  int idx = blockIdx.x * 256 + threadIdx.x;  // 0..131071
  int dir = idx >> 16, r = idx & 65535;
  int b = r >> 10, s = r & 1023;
  const u64* best = dir ? best_col : best_row;
  u64 p = best[r];
  int ind = (int)(0xFFFFFFFFu - (unsigned)(p & 0xFFFFFFFFull));
  int srcb = dir ? 64 + b : b, dstb = dir ? b : 64 + b;
  const uint4* rs = (const uint4*)(xT + (size_t)srcb * 131072 + (size_t)s * 128);
  const uint4* rd = (const uint4*)(xT + (size_t)dstb * 131072 + (size_t)ind * 128);
  float acc = 0.f;
#pragma unroll
  for (int i = 0; i < 8; ++i) {
    uint4 a = rs[i], d = rd[i];
    acc += bl16(a.x) * bl16(d.x) + bh16(a.x) * bh16(d.x);
    acc += bl16(a.y) * bl16(d.y) + bh16(a.y) * bh16(d.y);
    acc += bl16(a.z) * bl16(d.z) + bh16(a.z) * bh16(d.z);
    acc += bl16(a.w) * bl16(d.w) + bh16(a.w) * bh16(d.w);
  }
  float invs = x_invn[(dir ? 65536 : 0) + r];
  float invd = x_invn[(dir ? 0 : 65536) + b * 1024 + ind];
  posl[idx] = acc * invs * invd * TEMP_INV;
}

// ---------- neg: LDS-free MFMA GEMM + fused logsumexp ----------
// A = raw bf16 xT rows (per-row norm applied in epilogue — linear in row);
// B = ad16 [j][c] (k-contiguous natural layout). One atomic per block.
__global__ __launch_bounds__(256) void kneg(
    const __bf16* __restrict__ xT, const float* __restrict__ x_invn,
    const __bf16* __restrict__ ad16, const float* __restrict__ posl,
    float* __restrict__ dsum) {
  int st = blockIdx.x, b = blockIdx.y, dir = blockIdx.z;
  int t = threadIdx.x, lane = t & 63, w = t >> 6;
  int lc = lane & 15, q = lane >> 4;
  int sbase = st * 256 + w * 64;

  const __bf16* Ab = xT + (size_t)(dir * 64 + b) * 131072 + (size_t)sbase * 128 + q * 8;
  const __bf16* Bb = ad16 + dir * 8192 + q * 8;
  const float* invs = x_invn + (dir ? 65536 : 0) + b * 1024;
  const float* posb = posl + dir * 65536 + b * 1024;

  f32x4 acc[4][4];
#pragma unroll
  for (int i = 0; i < 4; ++i)
#pragma unroll
    for (int j = 0; j < 4; ++j) acc[i][j] = (f32x4)(0.f);

#pragma unroll
  for (int k = 0; k < 4; ++k) {  // k0 = k*32, K=128
    bf16x8 af[4], bfr[4];
#pragma unroll
    for (int i = 0; i < 4; ++i) af[i] = *(const bf16x8*)(Ab + (i * 16 + lc) * 128 + k * 32);
#pragma unroll
    for (int j = 0; j < 4; ++j) bfr[j] = *(const bf16x8*)(Bb + (j * 16 + lc) * 128 + k * 32);
#pragma unroll
    for (int i = 0; i < 4; ++i)
#pragma unroll
      for (int j = 0; j < 4; ++j)
        acc[i][j] = __builtin_amdgcn_mfma_f32_16x16x32_bf16(af[i], bfr[j], acc[i][j], 0, 0, 0);
  }

  float lsum = 0.f;
#pragma unroll
  for (int i = 0; i < 4; ++i) {
#pragma unroll
    for (int e = 0; e < 4; ++e) {
      int s = sbase + i * 16 + q * 4 + e;
      float sinv = invs[s];
      float lg[4];
      float mloc = -INFINITY;
#pragma unroll
      for (int jf = 0; jf < 4; ++jf) {
        int jg = jf * 16 + lc;
        lg[jf] = (jg == b) ? -INFINITY : acc[i][jf][e] * sinv * TEMP_INV;
        mloc = fmaxf(mloc, lg[jf]);
      }
#pragma unroll
      for (int mask = 1; mask <= 8; mask <<= 1) mloc = fmaxf(mloc, __shfl_xor(mloc, mask));
      float pos = posb[s];
      float m = fmaxf(mloc, pos);
      float es = 0.f;
#pragma unroll
      for (int jf = 0; jf < 4; ++jf) es += __expf(lg[jf] - m);
#pragma unroll
      for (int mask = 1; mask <= 8; mask <<= 1) es += __shfl_xor(es, mask);
      if (lc == 0) lsum += m + __logf(es + __expf(pos - m)) - pos;
    }
  }
  lsum += __shfl_xor(lsum, 16);
  lsum += __shfl_xor(lsum, 32);
  __shared__ float wred[4];
  if (lane == 0) wred[w] = lsum;
  __syncthreads();
  if (t == 0) atomicAdd(dsum, wred[0] + wred[1] + wred[2] + wred[3]);
}

// ---------- global loss (norms fused) ----------
__global__ void kglobal(const float* __restrict__ agq, const float* __restrict__ agk,
                        float* __restrict__ gsum) {
  __shared__ float logits[128];
  __shared__ float rinv[128];
  int i = blockIdx.x, j = threadIdx.x;
  const float* rowi = (i < 64) ? (agq + i * 128) : (agk + (i - 64) * 128);
  const float* rowj = (j < 64) ? (agq + j * 128) : (agk + (j - 64) * 128);
  float dot = 0.f, nj = 0.f;
#pragma unroll 8
  for (int c = 0; c < 128; ++c) { float a = rowi[c], bb = rowj[c]; dot += a * bb; nj += bb * bb; }
  rinv[j] = 1.0f / fmaxf(sqrtf(nj), 1e-12f);
  __syncthreads();
  logits[j] = dot * rinv[i] * rinv[j] * TEMP_INV;
  __syncthreads();
  if (j == 0) {
    int pos = (i + 64) & 127;
    float m = -INFINITY;
    for (int t = 0; t < 128; ++t) if (t != i) m = fmaxf(m, logits[t]);
    float e = 0.f;
    for (int t = 0; t < 128; ++t) if (t != i) e += __expf(logits[t] - m);
    atomicAdd(gsum, m + __logf(e) - logits[pos]);
  }
}

__global__ void kfinal(const float* __restrict__ gsum, const float* __restrict__ dsum,
                       const int* __restrict__ epoch, float* __restrict__ out) {
  if (threadIdx.x == 0) {
    float g = gsum[0] / 128.0f;
    float dn = dsum[0] / 131072.0f;
    out[0] = (epoch[0] > 0) ? (0.5f * g + 0.5f * dn) : g;  // WARMUP=0, COEFF=0.5
  }
}

// ---------- launch ----------
extern "C" void kernel_launch(void* const* d_in, const int* in_sizes, int n_in,
                              void* d_out, int out_size, void* d_ws, size_t ws_size,
                              hipStream_t stream) {
  const float* ofq = (const float*)d_in[0];
  const float* agq = (const float*)d_in[1];
  const float* xq  = (const float*)d_in[2];
  const float* adq = (const float*)d_in[3];
  const float* ofk = (const float*)d_in[4];
  const float* agk = (const float*)d_in[5];
  const float* xk  = (const float*)d_in[6];
  const float* adk = (const float*)d_in[7];
  const int* epoch = (const int*)d_in[8];
  float* out = (float*)d_out;

  // 64MB arena: ofT (kcvt..ksim), then reused as xT (kcvt_x..kneg).
  char* wsb = (char*)d_ws;
  __bf16* ofT = (__bf16*)wsb;                        // 64 MB
  __bf16* xT  = (__bf16*)wsb;                        // alias (ofT dead after ksim)
  u64* best_row = (u64*)(wsb + 67108864);            // 512 KB
  u64* best_col = best_row + 65536;                  // 512 KB
  float* posl = (float*)(best_col + 65536);          // 512 KB
  float* x_invn = posl + 131072;                     // 512 KB
  float* of_invn = x_invn + 131072;                  // 512 KB
  __bf16* ad16 = (__bf16*)(of_invn + 131072);        // 32 KB (16B-aligned)
  float* gsum = (float*)(ad16 + 16384);
  float* dsum = gsum + 1;

  hipMemsetAsync(best_row, 0, 65536ull * 8 * 2, stream);  // packed 0 < any real key
  hipMemsetAsync(gsum, 0, 8, stream);

  dim3 gc(32, 128);
  kcvt<<<gc, 256, 0, stream>>>(ofq, ofk, ofT, of_invn);
  kglobal<<<128, 128, 0, stream>>>(agq, agk, gsum);

  dim3 gs(8, 8, 64);
  ksim<<<gs, 256, 0, stream>>>(ofT, of_invn, best_row, best_col);

  dim3 gx(32, 129);
  kcvt_x<<<gx, 256, 0, stream>>>(xq, xk, xT, x_invn, adq, adk, ad16);

  kpos<<<512, 256, 0, stream>>>(xT, x_invn, best_row, best_col, posl);

  dim3 gn(4, 64, 2);
  kneg<<<gn, 256, 0, stream>>>(xT, x_invn, ad16, posl, dsum);

  kfinal<<<1, 1, 0, stream>>>(gsum, dsum, epoch, out);
}